// Round 1
// baseline (601.422 us; speedup 1.0000x reference)
//
#include <hip/hip_runtime.h>

#define D 64

// ---------------- setup kernels ----------------

__global__ void zero3_kernel(int* __restrict__ a, int* __restrict__ b,
                             int* __restrict__ c, int n) {
    int i = blockIdx.x * blockDim.x + threadIdx.x;
    if (i < n) { a[i] = 0; b[i] = 0; c[i] = 0; }
}

__global__ void hist_kernel(const int* __restrict__ src, const int* __restrict__ dst,
                            int* __restrict__ deg_src, int* __restrict__ deg_dst, int E) {
    int i = blockIdx.x * blockDim.x + threadIdx.x;
    if (i < E) {
        atomicAdd(&deg_src[src[i]], 1);
        atomicAdd(&deg_dst[dst[i]], 1);
    }
}

__global__ void norms_kernel(const int* __restrict__ deg_src, const int* __restrict__ deg_dst,
                             float* __restrict__ out_norm, float* __restrict__ in_norm, int n) {
    int i = blockIdx.x * blockDim.x + threadIdx.x;
    if (i < n) {
        out_norm[i] = rsqrtf((float)max(deg_src[i], 1));
        in_norm[i]  = rsqrtf((float)max(deg_dst[i], 1));
    }
}

// Scan step 1: per-block (1024 elements) totals.
__global__ void scan1_kernel(const int* __restrict__ deg, int* __restrict__ blk_tot, int n) {
    __shared__ int sdata[256];
    int tid = threadIdx.x;
    int base = blockIdx.x * 1024 + tid * 4;
    int s = 0;
#pragma unroll
    for (int j = 0; j < 4; j++) {
        int idx = base + j;
        s += (idx < n) ? deg[idx] : 0;
    }
    sdata[tid] = s;
    __syncthreads();
    for (int off = 128; off > 0; off >>= 1) {
        if (tid < off) sdata[tid] += sdata[tid + off];
        __syncthreads();
    }
    if (tid == 0) blk_tot[blockIdx.x] = sdata[0];
}

// Scan step 2: exclusive scan of block totals (single block, nb <= 1024).
__global__ void scan2_kernel(int* __restrict__ blk_tot, int nb) {
    __shared__ int tmp[1024];
    int tid = threadIdx.x;
    int v = (tid < nb) ? blk_tot[tid] : 0;
    tmp[tid] = v;
    __syncthreads();
    int val = v;
    for (int off = 1; off < 1024; off <<= 1) {
        int add = (tid >= off) ? tmp[tid - off] : 0;
        __syncthreads();
        val += add;
        tmp[tid] = val;
        __syncthreads();
    }
    if (tid < nb) blk_tot[tid] = val - v;  // exclusive
}

// Scan step 3: write exclusive row_ptr.
__global__ void scan3_kernel(const int* __restrict__ deg, const int* __restrict__ blk_tot,
                             int* __restrict__ row_ptr, int n, int E) {
    __shared__ int sdata[256];
    int tid = threadIdx.x;
    int base = blockIdx.x * 1024 + tid * 4;
    int v[4];
    int s = 0;
#pragma unroll
    for (int j = 0; j < 4; j++) {
        int idx = base + j;
        v[j] = (idx < n) ? deg[idx] : 0;
        s += v[j];
    }
    sdata[tid] = s;
    __syncthreads();
    int val = s;
    for (int off = 1; off < 256; off <<= 1) {
        int add = (tid >= off) ? sdata[tid - off] : 0;
        __syncthreads();
        val += add;
        sdata[tid] = val;
        __syncthreads();
    }
    int excl = blk_tot[blockIdx.x] + val - s;
#pragma unroll
    for (int j = 0; j < 4; j++) {
        int idx = base + j;
        if (idx < n) row_ptr[idx] = excl;
        excl += v[j];
    }
    if (blockIdx.x == 0 && tid == 0) row_ptr[n] = E;
}

__global__ void fill_csr_kernel(const int* __restrict__ src, const int* __restrict__ dst,
                                const int* __restrict__ row_ptr, int* __restrict__ cnt,
                                int* __restrict__ csr_src, int E) {
    int i = blockIdx.x * blockDim.x + threadIdx.x;
    if (i < E) {
        int d = dst[i];
        int p = row_ptr[d] + atomicAdd(&cnt[d], 1);
        csr_src[p] = src[i];
    }
}

// bufA = x * out_norm (row-broadcast), float4-vectorized. n4 = N * (D/4)
__global__ void scale_x_kernel(const float4* __restrict__ x, const float* __restrict__ out_norm,
                               float4* __restrict__ out, int n4) {
    int i = blockIdx.x * blockDim.x + threadIdx.x;
    if (i < n4) {
        int node = i >> 4;  // D/4 == 16 float4 per row
        float s = out_norm[node];
        float4 v = x[i];
        v.x *= s; v.y *= s; v.z *= s; v.w *= s;
        out[i] = v;
    }
}

// One GCN layer: wave per node, lane = feature.
//   agg[lane]  = sum_{e in in-edges(v)} h_in_scaled[src(e)][lane]
//   agg       *= in_norm[v]
//   o[lane]    = b[lane] + sum_k agg[k] * W[k][lane]   (shfl-broadcast GEMM, W in LDS)
//   if relu_scale: o = relu(o) * out_norm[v]           (pre-scale for next layer)
__global__ __launch_bounds__(256) void layer_kernel(
    const float* __restrict__ hin, const int* __restrict__ csr_src,
    const int* __restrict__ row_ptr, const float* __restrict__ in_norm,
    const float* __restrict__ out_norm, const float* __restrict__ W,
    const float* __restrict__ bias, float* __restrict__ hout,
    int n, int relu_scale) {
    __shared__ float Ws[D * D];
    int tid = threadIdx.x;
    // cooperative W load (float4)
    const float4* W4 = (const float4*)W;
    float4* Ws4 = (float4*)Ws;
#pragma unroll
    for (int i = tid; i < D * D / 4; i += 256) Ws4[i] = W4[i];
    __syncthreads();

    int wave = tid >> 6;
    int lane = tid & 63;
    int v = blockIdx.x * 4 + wave;
    if (v >= n) return;  // no barriers after this point

    int begin = row_ptr[v];
    int end = row_ptr[v + 1];

    float acc = 0.f;
    int i = begin;
    for (; i + 4 <= end; i += 4) {
        int s0 = csr_src[i];
        int s1 = csr_src[i + 1];
        int s2 = csr_src[i + 2];
        int s3 = csr_src[i + 3];
        float v0 = hin[s0 * D + lane];
        float v1 = hin[s1 * D + lane];
        float v2 = hin[s2 * D + lane];
        float v3 = hin[s3 * D + lane];
        acc += v0 + v1 + v2 + v3;
    }
    for (; i < end; ++i) acc += hin[csr_src[i] * D + lane];

    acc *= in_norm[v];

    float o = bias[lane];
#pragma unroll
    for (int k = 0; k < D; k++) {
        float a = __shfl(acc, k, 64);
        o = fmaf(a, Ws[k * D + lane], o);
    }

    if (relu_scale) {
        o = fmaxf(o, 0.f) * out_norm[v];
    }
    hout[v * D + lane] = o;
}

// ---------------- launch ----------------

extern "C" void kernel_launch(void* const* d_in, const int* in_sizes, int n_in,
                              void* d_out, int out_size, void* d_ws, size_t ws_size,
                              hipStream_t stream) {
    const float* x  = (const float*)d_in[0];
    const int* src  = (const int*)d_in[1];
    const int* dst  = (const int*)d_in[2];
    const float* W1 = (const float*)d_in[3];
    const float* b1 = (const float*)d_in[4];
    const float* W2 = (const float*)d_in[5];
    const float* b2 = (const float*)d_in[6];
    const float* W3 = (const float*)d_in[7];
    const float* b3 = (const float*)d_in[8];

    const int N = in_sizes[0] / D;
    const int E = in_sizes[1];

    char* ws = (char*)d_ws;
    size_t off = 0;
    auto alloc = [&](size_t elems) -> void* {
        void* p = (void*)(ws + off);
        off += ((elems + 3) / 4) * 16;  // pad to 16B
        return p;
    };
    int* deg_src   = (int*)alloc(N);
    int* deg_dst   = (int*)alloc(N);
    int* cnt       = (int*)alloc(N);
    int* row_ptr   = (int*)alloc(N + 1);
    int* blk_tot   = (int*)alloc(1024);
    float* out_nrm = (float*)alloc(N);
    float* in_nrm  = (float*)alloc(N);
    int* csr_src   = (int*)alloc(E);
    float* bufA    = (float*)alloc((size_t)N * D);
    float* bufB    = (float*)alloc((size_t)N * D);

    const int B = 256;
    zero3_kernel<<<(N + B - 1) / B, B, 0, stream>>>(deg_src, deg_dst, cnt, N);
    hist_kernel<<<(E + B - 1) / B, B, 0, stream>>>(src, dst, deg_src, deg_dst, E);
    norms_kernel<<<(N + B - 1) / B, B, 0, stream>>>(deg_src, deg_dst, out_nrm, in_nrm, N);

    int nb = (N + 1023) / 1024;
    scan1_kernel<<<nb, 256, 0, stream>>>(deg_dst, blk_tot, N);
    scan2_kernel<<<1, 1024, 0, stream>>>(blk_tot, nb);
    scan3_kernel<<<nb, 256, 0, stream>>>(deg_dst, blk_tot, row_ptr, N, E);

    fill_csr_kernel<<<(E + B - 1) / B, B, 0, stream>>>(src, dst, row_ptr, cnt, csr_src, E);

    int n4 = N * (D / 4);
    scale_x_kernel<<<(n4 + B - 1) / B, B, 0, stream>>>((const float4*)x, out_nrm,
                                                       (float4*)bufA, n4);

    int lgrid = (N + 3) / 4;
    layer_kernel<<<lgrid, 256, 0, stream>>>(bufA, csr_src, row_ptr, in_nrm, out_nrm,
                                            W1, b1, bufB, N, 1);
    layer_kernel<<<lgrid, 256, 0, stream>>>(bufB, csr_src, row_ptr, in_nrm, out_nrm,
                                            W2, b2, bufA, N, 1);
    layer_kernel<<<lgrid, 256, 0, stream>>>(bufA, csr_src, row_ptr, in_nrm, out_nrm,
                                            W3, b3, (float*)d_out, N, 0);
}

// Round 2
// 510.651 us; speedup vs baseline: 1.1778x; 1.1778x over previous
//
#include <hip/hip_runtime.h>

#define D 64

// ---------------- setup kernels ----------------

__global__ void hist_kernel(const int* __restrict__ src, const int* __restrict__ dst,
                            int* __restrict__ deg_src, int* __restrict__ deg_dst, int E) {
    int i = blockIdx.x * blockDim.x + threadIdx.x;
    if (i < E) {
        atomicAdd(&deg_src[src[i]], 1);
        atomicAdd(&deg_dst[dst[i]], 1);
    }
}

// Scan step 1: per-block (1024 elements) totals of deg_dst.
__global__ void scan1_kernel(const int* __restrict__ deg, int* __restrict__ blk_tot, int n) {
    __shared__ int sdata[256];
    int tid = threadIdx.x;
    int base = blockIdx.x * 1024 + tid * 4;
    int s = 0;
#pragma unroll
    for (int j = 0; j < 4; j++) {
        int idx = base + j;
        s += (idx < n) ? deg[idx] : 0;
    }
    sdata[tid] = s;
    __syncthreads();
    for (int off = 128; off > 0; off >>= 1) {
        if (tid < off) sdata[tid] += sdata[tid + off];
        __syncthreads();
    }
    if (tid == 0) blk_tot[blockIdx.x] = sdata[0];
}

// Scan step 2: exclusive scan of block totals (single block, nb <= 1024).
__global__ void scan2_kernel(int* __restrict__ blk_tot, int nb) {
    __shared__ int tmp[1024];
    int tid = threadIdx.x;
    int v = (tid < nb) ? blk_tot[tid] : 0;
    tmp[tid] = v;
    __syncthreads();
    int val = v;
    for (int off = 1; off < 1024; off <<= 1) {
        int add = (tid >= off) ? tmp[tid - off] : 0;
        __syncthreads();
        val += add;
        tmp[tid] = val;
        __syncthreads();
    }
    if (tid < nb) blk_tot[tid] = val - v;  // exclusive
}

// Scan step 3: write exclusive row_ptr, plus both degree norms (fused).
__global__ void scan3_norms_kernel(const int* __restrict__ deg_dst, const int* __restrict__ deg_src,
                                   const int* __restrict__ blk_tot, int* __restrict__ row_ptr,
                                   float* __restrict__ out_norm, float* __restrict__ in_norm,
                                   int n, int E) {
    __shared__ int sdata[256];
    int tid = threadIdx.x;
    int base = blockIdx.x * 1024 + tid * 4;
    int v[4];
    int s = 0;
#pragma unroll
    for (int j = 0; j < 4; j++) {
        int idx = base + j;
        v[j] = (idx < n) ? deg_dst[idx] : 0;
        s += v[j];
    }
    sdata[tid] = s;
    __syncthreads();
    int val = s;
    for (int off = 1; off < 256; off <<= 1) {
        int add = (tid >= off) ? sdata[tid - off] : 0;
        __syncthreads();
        val += add;
        sdata[tid] = val;
        __syncthreads();
    }
    int excl = blk_tot[blockIdx.x] + val - s;
#pragma unroll
    for (int j = 0; j < 4; j++) {
        int idx = base + j;
        if (idx < n) {
            row_ptr[idx] = excl;
            in_norm[idx] = rsqrtf((float)max(v[j], 1));
            out_norm[idx] = rsqrtf((float)max(deg_src[idx], 1));
        }
        excl += v[j];
    }
    if (blockIdx.x == 0 && tid == 0) row_ptr[n] = E;
}

__global__ void fill_csr_kernel(const int* __restrict__ src, const int* __restrict__ dst,
                                const int* __restrict__ row_ptr, int* __restrict__ cnt,
                                int* __restrict__ csr_src, int E) {
    int i = blockIdx.x * blockDim.x + threadIdx.x;
    if (i < E) {
        int d = dst[i];
        int p = row_ptr[d] + atomicAdd(&cnt[d], 1);
        csr_src[p] = src[i];
    }
}

// ---------------- fused layer kernel ----------------
// Wave per node v. Lanes: 4 edge-groups x 16 feature-lanes, float4 per lane.
//   acc = sum over in-edges of hin[src]  (optionally * out_norm[src] for layer 1)
//   reduce edge groups (shfl), acc *= in_norm[v]
//   GEMM: o[lane] = sum_k acc_k * W[k][lane]  via v_readlane broadcasts (VALU, not LDS pipe)
//   o += bias; optionally relu + pre-scale by out_norm[v] for the next layer's gather.
#define RL(comp, l) __int_as_float(__builtin_amdgcn_readlane(__float_as_int(comp), (l)))

__global__ __launch_bounds__(256) void layer_kernel(
    const float* __restrict__ hin, const int* __restrict__ csr_src,
    const int* __restrict__ row_ptr, const float* __restrict__ in_norm,
    const float* __restrict__ out_norm, const float* __restrict__ W,
    const float* __restrict__ bias, float* __restrict__ hout,
    int n, int scale_src, int relu_out) {
    int tid = threadIdx.x;
    int lane = tid & 63;
    int v = blockIdx.x * 4 + (tid >> 6);
    if (v >= n) return;  // no barriers used anywhere

    // Preload W column slice into 64 VGPRs: w[k] = W[k][lane]. Hot in L1 (16 KB).
    float w[D];
#pragma unroll
    for (int k = 0; k < D; k++) w[k] = W[k * D + lane];

    int begin = row_ptr[v];
    int end = row_ptr[v + 1];
    int eg = lane >> 4;   // edge group 0..3
    int fl = lane & 15;   // feature float4 index 0..15

    const float4* hin4 = (const float4*)hin;
    float4 acc = make_float4(0.f, 0.f, 0.f, 0.f);
    for (int e = begin + eg; e < end; e += 4) {
        int s = csr_src[e];
        float4 vv = hin4[(size_t)s * 16 + fl];
        if (scale_src) {
            float sc = out_norm[s];
            vv.x *= sc; vv.y *= sc; vv.z *= sc; vv.w *= sc;
        }
        acc.x += vv.x; acc.y += vv.y; acc.z += vv.z; acc.w += vv.w;
    }

    // reduce 4 edge groups -> lanes 0..15 hold the full row sum
    acc.x += __shfl_down(acc.x, 32); acc.y += __shfl_down(acc.y, 32);
    acc.z += __shfl_down(acc.z, 32); acc.w += __shfl_down(acc.w, 32);
    acc.x += __shfl_down(acc.x, 16); acc.y += __shfl_down(acc.y, 16);
    acc.z += __shfl_down(acc.z, 16); acc.w += __shfl_down(acc.w, 16);

    float inv = in_norm[v];
    acc.x *= inv; acc.y *= inv; acc.z *= inv; acc.w *= inv;

    // GEMM via readlane broadcast: lane kq holds features 4kq..4kq+3 in acc.xyzw
    float o0 = bias[lane], o1 = 0.f, o2 = 0.f, o3 = 0.f;
#pragma unroll
    for (int kq = 0; kq < 16; kq++) {
        float a0 = RL(acc.x, kq);
        float a1 = RL(acc.y, kq);
        float a2 = RL(acc.z, kq);
        float a3 = RL(acc.w, kq);
        o0 = fmaf(a0, w[4 * kq + 0], o0);
        o1 = fmaf(a1, w[4 * kq + 1], o1);
        o2 = fmaf(a2, w[4 * kq + 2], o2);
        o3 = fmaf(a3, w[4 * kq + 3], o3);
    }
    float o = (o0 + o1) + (o2 + o3);

    if (relu_out) o = fmaxf(o, 0.f) * out_norm[v];
    hout[(size_t)v * D + lane] = o;
}

// ---------------- launch ----------------

extern "C" void kernel_launch(void* const* d_in, const int* in_sizes, int n_in,
                              void* d_out, int out_size, void* d_ws, size_t ws_size,
                              hipStream_t stream) {
    const float* x  = (const float*)d_in[0];
    const int* src  = (const int*)d_in[1];
    const int* dst  = (const int*)d_in[2];
    const float* W1 = (const float*)d_in[3];
    const float* b1 = (const float*)d_in[4];
    const float* W2 = (const float*)d_in[5];
    const float* b2 = (const float*)d_in[6];
    const float* W3 = (const float*)d_in[7];
    const float* b3 = (const float*)d_in[8];

    const int N = in_sizes[0] / D;
    const int E = in_sizes[1];

    char* ws = (char*)d_ws;
    size_t off = 0;
    auto alloc = [&](size_t elems) -> void* {
        void* p = (void*)(ws + off);
        off += ((elems + 3) / 4) * 16;  // pad to 16B
        return p;
    };
    // deg_src, deg_dst, cnt kept contiguous for a single memset (N*4 % 16 == 0)
    int* deg_src   = (int*)alloc(N);
    int* deg_dst   = (int*)alloc(N);
    int* cnt       = (int*)alloc(N);
    int* row_ptr   = (int*)alloc(N + 1);
    int* blk_tot   = (int*)alloc(1024);
    float* out_nrm = (float*)alloc(N);
    float* in_nrm  = (float*)alloc(N);
    int* csr_src   = (int*)alloc(E);
    float* bufA    = (float*)alloc((size_t)N * D);
    float* bufB    = (float*)alloc((size_t)N * D);

    const int B = 256;
    hipMemsetAsync(deg_src, 0, (size_t)3 * N * sizeof(int), stream);
    hist_kernel<<<(E + B - 1) / B, B, 0, stream>>>(src, dst, deg_src, deg_dst, E);

    int nb = (N + 1023) / 1024;
    scan1_kernel<<<nb, 256, 0, stream>>>(deg_dst, blk_tot, N);
    scan2_kernel<<<1, 1024, 0, stream>>>(blk_tot, nb);
    scan3_norms_kernel<<<nb, 256, 0, stream>>>(deg_dst, deg_src, blk_tot, row_ptr,
                                               out_nrm, in_nrm, N, E);

    fill_csr_kernel<<<(E + B - 1) / B, B, 0, stream>>>(src, dst, row_ptr, cnt, csr_src, E);

    int lgrid = (N + 3) / 4;
    // layer 1: gather x scaled by out_norm[src] on the fly; epilogue relu * out_norm
    layer_kernel<<<lgrid, 256, 0, stream>>>(x, csr_src, row_ptr, in_nrm, out_nrm,
                                            W1, b1, bufB, N, 1, 1);
    // layer 2: input already pre-scaled
    layer_kernel<<<lgrid, 256, 0, stream>>>(bufB, csr_src, row_ptr, in_nrm, out_nrm,
                                            W2, b2, bufA, N, 0, 1);
    // layer 3: final — bias only, no relu, no pre-scale
    layer_kernel<<<lgrid, 256, 0, stream>>>(bufA, csr_src, row_ptr, in_nrm, out_nrm,
                                            W3, b3, (float*)d_out, N, 0, 0);
}